// Round 5
// baseline (1085.144 us; speedup 1.0000x reference)
//
#include <hip/hip_runtime.h>

// GCN 2-layer forward (Hu et al. mol-GNN variant), fp32.
// R5: zero-global-atomic pipeline. R4 showed device-scope atomics to random lines
// cap at ~20-25 G line-RMW/s (histogram 79us, fill similar). Replace histogram +
// scan + fill CSR build with a 782-bucket counting-sort partition (LDS histograms,
// 2-level scan, LDS-cursor placement, plain stores), and aggregate per bucket in a
// 32KB LDS fp32 accumulator (ds_add_f32), stride-68 padded against bank conflicts.
//
//   dis[n] = 1/sqrt(1 + outdeg(n))
//   per layer: h = X@W.T + b
//              out[n] = dis[n]^2*(h[n]+emb_self) + sum_{e: dst=n} dis[s]*dis[n]*(h[s]+emb_e)
//   ReLU fused into GEMM2 input read.
//
// Payload: src(17b) | embIdx(5b)<<17 | dstLow7(7b)<<22   (N<2^17, emb=bt*3+bd<18)
// Workspace ~36 MB (proven-safe budget: R1's 51.6 MB passed, R2's 61.2 MB overflowed).

#define THREADS 256
#define PB 256      // partition pass blocks
#define MAXNB 1024  // max buckets (supports N <= 131072)

// ---- P1: per-block coarse histograms over src-buckets and dst-buckets ----
__global__ __launch_bounds__(THREADS) void part_count_kernel(
    const int* __restrict__ src, const int* __restrict__ dst,
    int* __restrict__ countsS, int* __restrict__ countsD,  // [MAXNB*PB], bucket-major
    int E, int NB) {
    __shared__ int hS[MAXNB], hD[MAXNB];
    int t = threadIdx.x, b = blockIdx.x;
    for (int k = t; k < NB; k += THREADS) { hS[k] = 0; hD[k] = 0; }
    __syncthreads();
    int chunk = (E + PB - 1) / PB;
    int lo = b * chunk, hi = min(E, lo + chunk);
    for (int i = lo + t; i < hi; i += THREADS) {
        atomicAdd(&hS[src[i] >> 7], 1);
        atomicAdd(&hD[dst[i] >> 7], 1);
    }
    __syncthreads();
    for (int k = t; k < NB; k += THREADS) {
        countsS[k * PB + b] = hS[k];
        countsD[k * PB + b] = hD[k];
    }
}

// ---- P2a: per-bucket exclusive scan over the PB per-block counts (in place) ----
__global__ __launch_bounds__(THREADS) void part_scanblocks_kernel(
    int* __restrict__ countsS, int* __restrict__ countsD,
    int* __restrict__ totalS, int* __restrict__ totalD) {
    __shared__ int s[THREADS];
    int t = threadIdx.x, k = blockIdx.x;

    int v = countsS[k * PB + t];
    s[t] = v;
    __syncthreads();
    for (int d = 1; d < THREADS; d <<= 1) {
        int a = (t >= d) ? s[t - d] : 0;
        __syncthreads();
        s[t] += a;
        __syncthreads();
    }
    countsS[k * PB + t] = s[t] - v;
    if (t == THREADS - 1) totalS[k] = s[t];
    __syncthreads();

    v = countsD[k * PB + t];
    s[t] = v;
    __syncthreads();
    for (int d = 1; d < THREADS; d <<= 1) {
        int a = (t >= d) ? s[t - d] : 0;
        __syncthreads();
        s[t] += a;
        __syncthreads();
    }
    countsD[k * PB + t] = s[t] - v;
    if (t == THREADS - 1) totalD[k] = s[t];
}

// ---- P2b: exclusive scan of bucket totals -> bucket base offsets (NB <= 1024) ----
__global__ __launch_bounds__(THREADS) void part_scanbase_kernel(
    const int* __restrict__ totalS, const int* __restrict__ totalD,
    int* __restrict__ baseS, int* __restrict__ baseD, int NB) {
    __shared__ int s[THREADS];
    int t = threadIdx.x;
#pragma unroll 1
    for (int pass = 0; pass < 2; ++pass) {
        const int* in = pass ? totalD : totalS;
        int* out = pass ? baseD : baseS;
        int base = t * 4;
        int v[4];
#pragma unroll
        for (int k = 0; k < 4; ++k) v[k] = (base + k < NB) ? in[base + k] : 0;
        s[t] = v[0] + v[1] + v[2] + v[3];
        __syncthreads();
        for (int d = 1; d < THREADS; d <<= 1) {
            int a = (t >= d) ? s[t - d] : 0;
            __syncthreads();
            s[t] += a;
            __syncthreads();
        }
        int off = (t == 0) ? 0 : s[t - 1];
#pragma unroll
        for (int k = 0; k < 4; ++k) {
            if (base + k < NB) out[base + k] = off;
            off += v[k];
        }
        __syncthreads();
    }
}

// ---- P3: placement pass (same chunking as P1), plain stores, LDS cursors ----
__global__ __launch_bounds__(THREADS) void part_scatter_kernel(
    const int* __restrict__ src, const int* __restrict__ dst, const int* __restrict__ attr,
    const int* __restrict__ countsS, const int* __restrict__ countsD,
    const int* __restrict__ baseS, const int* __restrict__ baseD,
    int* __restrict__ payS, int* __restrict__ payD, int E, int NB) {
    __shared__ int curS[MAXNB], curD[MAXNB];
    int t = threadIdx.x, b = blockIdx.x;
    for (int k = t; k < NB; k += THREADS) {
        curS[k] = baseS[k] + countsS[k * PB + b];
        curD[k] = baseD[k] + countsD[k * PB + b];
    }
    __syncthreads();
    int chunk = (E + PB - 1) / PB;
    int lo = b * chunk, hi = min(E, lo + chunk);
    const int2* ap = (const int2*)attr;
    for (int i = lo + t; i < hi; i += THREADS) {
        int sv = src[i], dv = dst[i];
        int2 a = ap[i];
        int pS = atomicAdd(&curS[sv >> 7], 1);  // LDS atomic
        payS[pS] = sv & 127;
        int pD = atomicAdd(&curD[dv >> 7], 1);  // LDS atomic
        payD[pD] = sv | ((a.x * 3 + a.y) << 17) | ((dv & 127) << 22);
    }
}

// ---- P4: exact out-degree per node from src-grouped values -> dis ----
__global__ __launch_bounds__(THREADS) void deg_dis_kernel(
    const int* __restrict__ payS, const int* __restrict__ baseS,
    const int* __restrict__ totalS, float* __restrict__ disv, int N) {
    __shared__ int cnt[128];
    int t = threadIdx.x, k = blockIdx.x;
    if (t < 128) cnt[t] = 0;
    __syncthreads();
    int off = baseS[k], n = totalS[k];
    for (int i = t; i < n; i += THREADS) atomicAdd(&cnt[payS[off + i]], 1);
    __syncthreads();
    if (t < 128) {
        int node = k * 128 + t;
        if (node < N) disv[node] = 1.0f / sqrtf(1.0f + (float)cnt[t]);
    }
}

// ---- GEMM: H = X @ W.T + B. 4-wave blocks, 64-row tile; wave w owns cols [16w,16w+16).
// W/B reads wave-uniform -> scalar loads; stores staged via LDS (R3: 3.4x write amp fix).
template <bool RELU_IN>
__global__ __launch_bounds__(THREADS) void gemm64_kernel(const float* __restrict__ X,
                                                         const float* __restrict__ W,
                                                         const float* __restrict__ B,
                                                         float* __restrict__ H, int N) {
    __shared__ float smem[64][68];
    int t = threadIdx.x;
    int lane = t & 63;
    int wave = __builtin_amdgcn_readfirstlane(t >> 6);
    int row = blockIdx.x * 64 + lane;

    const float* Wp = W + wave * (16 * 64);
    const float* Bp = B + wave * 16;

    float xr[64];
    if (row < N) {
        const float4* xp = (const float4*)(X + (size_t)row * 64);
#pragma unroll
        for (int m = 0; m < 16; ++m) {
            float4 v = xp[m];
            if (RELU_IN) {
                v.x = fmaxf(v.x, 0.0f);
                v.y = fmaxf(v.y, 0.0f);
                v.z = fmaxf(v.z, 0.0f);
                v.w = fmaxf(v.w, 0.0f);
            }
            xr[4 * m + 0] = v.x;
            xr[4 * m + 1] = v.y;
            xr[4 * m + 2] = v.z;
            xr[4 * m + 3] = v.w;
        }
    } else {
#pragma unroll
        for (int k = 0; k < 64; ++k) xr[k] = 0.0f;
    }

    float acc[16];
#pragma unroll
    for (int j = 0; j < 16; ++j) acc[j] = Bp[j];
#pragma unroll
    for (int k = 0; k < 64; ++k) {
        float xk = xr[k];
#pragma unroll
        for (int j = 0; j < 16; ++j) acc[j] = fmaf(xk, Wp[j * 64 + k], acc[j]);
    }

#pragma unroll
    for (int j4 = 0; j4 < 4; ++j4) {
        *(float4*)(&smem[lane][wave * 16 + j4 * 4]) =
            make_float4(acc[4 * j4], acc[4 * j4 + 1], acc[4 * j4 + 2], acc[4 * j4 + 3]);
    }
    __syncthreads();

#pragma unroll
    for (int i = 0; i < 4; ++i) {
        int idx = t + i * THREADS;
        int r = idx >> 4;
        int c = (idx & 15) << 2;
        int grow = blockIdx.x * 64 + r;
        if (grow < N) *(float4*)(H + (size_t)grow * 64 + c) = *(const float4*)(&smem[r][c]);
    }
}

// ---- Aggregate per dst-bucket: LDS fp32 accumulators (stride 68 vs bank conflicts) ----
// out[n] = dis[n]^2*(H[n]+embc[12]) + sum_{e:dst=n} dis[s]*dis[n]*(H[s]+embc[ei])
__global__ __launch_bounds__(THREADS) void aggregate_kernel(
    const float* __restrict__ H, const float* __restrict__ disv,
    const float* __restrict__ ebond, const float* __restrict__ edir,
    const int* __restrict__ payD, const int* __restrict__ baseD,
    const int* __restrict__ totalD, float* __restrict__ out, int N) {
    __shared__ float acc[128 * 68];
    __shared__ float embc[18 * 64];
    __shared__ float disL[128];
    int t = threadIdx.x, k = blockIdx.x;

    for (int i = t; i < 128 * 68; i += THREADS) acc[i] = 0.0f;
    for (int i = t; i < 18 * 64; i += THREADS) {
        int r = i >> 6, c = i & 63;
        embc[i] = ebond[(r / 3) * 64 + c] + edir[(r % 3) * 64 + c];
    }
    if (t < 128) {
        int node = k * 128 + t;
        disL[t] = (node < N) ? disv[node] : 0.0f;
    }
    __syncthreads();

    int eoff = baseD[k], ecnt = totalD[k];
    int g = t >> 4;           // 16 edge-groups of 16 lanes
    int c = (t & 15) << 2;    // 4 dims per lane
    for (int p = g; p < ecnt; p += 16) {
        int u = payD[eoff + p];
        int s = u & 0x1FFFF;
        int ei = (u >> 17) & 31;
        int dl = (u >> 22) & 127;
        float w = disv[s] * disL[dl];
        float4 h = *(const float4*)(H + (size_t)s * 64 + c);
        float4 e = *(const float4*)(&embc[ei * 64 + c]);
        float* a = &acc[dl * 68 + c];
        atomicAdd(a + 0, w * (h.x + e.x));
        atomicAdd(a + 1, w * (h.y + e.y));
        atomicAdd(a + 2, w * (h.z + e.z));
        atomicAdd(a + 3, w * (h.w + e.w));
    }
    __syncthreads();

    for (int idx = t; idx < 128 * 16; idx += THREADS) {
        int j = idx >> 4;
        int cc = (idx & 15) << 2;
        int n = k * 128 + j;
        if (n < N) {
            float dn = disL[j];
            float nrm = dn * dn;
            float4 h = *(const float4*)(H + (size_t)n * 64 + cc);
            float4 e = *(const float4*)(&embc[12 * 64 + cc]);
            float4 a = *(const float4*)(&acc[j * 68 + cc]);
            float4 o;
            o.x = a.x + nrm * (h.x + e.x);
            o.y = a.y + nrm * (h.y + e.y);
            o.z = a.z + nrm * (h.z + e.z);
            o.w = a.w + nrm * (h.w + e.w);
            *(float4*)(out + (size_t)n * 64 + cc) = o;
        }
    }
}

extern "C" void kernel_launch(void* const* d_in, const int* in_sizes, int n_in,
                              void* d_out, int out_size, void* d_ws, size_t ws_size,
                              hipStream_t stream) {
    const float* x      = (const float*)d_in[0];
    const int*   eidx   = (const int*)d_in[1];
    const int*   eattr  = (const int*)d_in[2];
    const float* W1     = (const float*)d_in[3];
    const float* b1     = (const float*)d_in[4];
    const float* ebond1 = (const float*)d_in[5];
    const float* edir1  = (const float*)d_in[6];
    const float* W2     = (const float*)d_in[7];
    const float* b2     = (const float*)d_in[8];
    const float* ebond2 = (const float*)d_in[9];
    const float* edir2  = (const float*)d_in[10];

    const int N = in_sizes[0] / 64;
    const int E = in_sizes[1] / 2;
    const int* src = eidx;
    const int* dst = eidx + E;
    float* out = (float*)d_out;
    const int NB = (N + 127) / 128;  // dst/src buckets of 128 nodes

    // Workspace (~36 MB)
    char* w = (char*)d_ws;
    size_t Na = ((size_t)N * 4 + 255) & ~(size_t)255;
    size_t Ea = ((size_t)E * 4 + 255) & ~(size_t)255;
    float* disv    = (float*)w;  w += Na;
    int*   countsS = (int*)w;    w += (size_t)MAXNB * PB * 4;  // 1 MB
    int*   countsD = (int*)w;    w += (size_t)MAXNB * PB * 4;  // 1 MB
    int*   totalS  = (int*)w;    w += MAXNB * 4;
    int*   totalD  = (int*)w;    w += MAXNB * 4;
    int*   baseS   = (int*)w;    w += MAXNB * 4;
    int*   baseD   = (int*)w;    w += MAXNB * 4;
    int*   payS    = (int*)w;    w += Ea;                      // 4 MB
    int*   payD    = (int*)w;    w += Ea;                      // 4 MB
    float* bufA    = (float*)w;  w += (size_t)N * 64 * 4;      // 25.6 MB

    const int gG = (N + 63) / 64;  // gemm tiles

    // Partition build (zero global atomics); graph shared by both layers.
    part_count_kernel<<<PB, THREADS, 0, stream>>>(src, dst, countsS, countsD, E, NB);
    part_scanblocks_kernel<<<NB, THREADS, 0, stream>>>(countsS, countsD, totalS, totalD);
    part_scanbase_kernel<<<1, THREADS, 0, stream>>>(totalS, totalD, baseS, baseD, NB);
    part_scatter_kernel<<<PB, THREADS, 0, stream>>>(src, dst, eattr, countsS, countsD, baseS,
                                                    baseD, payS, payD, E, NB);
    deg_dis_kernel<<<NB, THREADS, 0, stream>>>(payS, baseS, totalS, disv, N);

    // layer 1: h -> bufA, aggregate -> d_out (temp)
    gemm64_kernel<false><<<gG, THREADS, 0, stream>>>(x, W1, b1, bufA, N);
    aggregate_kernel<<<NB, THREADS, 0, stream>>>(bufA, disv, ebond1, edir1, payD, baseD, totalD,
                                                 out, N);

    // layer 2 (ReLU fused into GEMM input read): out -> bufA -> out
    gemm64_kernel<true><<<gG, THREADS, 0, stream>>>(out, W2, b2, bufA, N);
    aggregate_kernel<<<NB, THREADS, 0, stream>>>(bufA, disv, ebond2, edir2, payD, baseD, totalD,
                                                 out, N);
}

// Round 6
// 406.670 us; speedup vs baseline: 2.6684x; 2.6684x over previous
//
#include <hip/hip_runtime.h>

// GCN 2-layer forward (Hu et al. mol-GNN variant), fp32 — CSR aggregation.
//
//   dis[n] = 1/sqrt(1 + outdeg(n))
//   per layer: h = X@W.T + b
//              out[n] = dis[n]^2*(h[n]+emb_self) + sum_{e: dst=n} dis[s]*dis[n]*(h[s]+emb_e)
//   ReLU fused into GEMM2 input read.
//
// R6 notes:
//  - R5's bucket-LDS aggregate regressed 6x (stride-68 acc => all ds_atomics on banks
//    %4==0 => 8-way conflict; grid 782 => occupancy 22%). Reverted to R4 CSR aggregate.
//  - histogram: counters replicated x8 (blockIdx&7). With round-robin block->XCD
//    dispatch each replica's atomic RMW stays in its XCD-local L2 instead of
//    ping-ponging lines across XCDs through HBM (R4: 62 MB WRITE_SIZE, 79 us).
//    Correctness never depends on the mapping (plain device atomics + reduce pass).
//  - aggregate edge loop unrolled 2-wide (independent accumulators) for gather MLP.
// Workspace ~37.6 MB (proven-safe: R1's 51.6 MB passed; R2's 61.2 MB overflowed).

#define THREADS 256
#define NREP 8  // histogram replicas (one per XCD under round-robin dispatch)

__global__ __launch_bounds__(THREADS) void zero_kernel(int* __restrict__ p, int n) {
    int i = blockIdx.x * THREADS + threadIdx.x;
    if (i < n) p[i] = 0;
}

// Replicated histograms: copy = blockIdx & 7 keeps each replica XCD-local (perf hint only).
__global__ __launch_bounds__(THREADS) void histogram8_kernel(const int* __restrict__ src,
                                                             const int* __restrict__ dst,
                                                             int* __restrict__ srcdeg8,
                                                             int* __restrict__ dstcnt8,
                                                             int strideI, int E) {
    int i = blockIdx.x * THREADS + threadIdx.x;
    if (i >= E) return;
    int c = blockIdx.x & (NREP - 1);
    atomicAdd(&srcdeg8[c * strideI + src[i]], 1);
    atomicAdd(&dstcnt8[c * strideI + dst[i]], 1);
}

// Fold replicas: dis[n] = rsqrt(1+outdeg), dst_cnt[n] = indeg.
__global__ __launch_bounds__(THREADS) void reduce8_kernel(const int* __restrict__ srcdeg8,
                                                          const int* __restrict__ dstcnt8,
                                                          float* __restrict__ disv,
                                                          int* __restrict__ dst_cnt,
                                                          int strideI, int N) {
    int i = blockIdx.x * THREADS + threadIdx.x;
    if (i >= N) return;
    int s = 0, d = 0;
#pragma unroll
    for (int c = 0; c < NREP; ++c) {
        s += srcdeg8[c * strideI + i];
        d += dstcnt8[c * strideI + i];
    }
    disv[i] = 1.0f / sqrtf(1.0f + (float)s);
    dst_cnt[i] = d;
}

// Block-local exclusive scan: block b handles cnt[b*1024 .. b*1024+1023], 4 elems/thread.
__global__ __launch_bounds__(THREADS) void scan1_kernel(const int* __restrict__ cnt,
                                                        int* __restrict__ row_ptr,
                                                        int* __restrict__ bsum, int N) {
    __shared__ int s[THREADS];
    int t = threadIdx.x;
    int base = blockIdx.x * 1024 + t * 4;
    int v[4];
#pragma unroll
    for (int k = 0; k < 4; ++k) v[k] = (base + k < N) ? cnt[base + k] : 0;
    int sum4 = v[0] + v[1] + v[2] + v[3];
    s[t] = sum4;
    __syncthreads();
    for (int d = 1; d < THREADS; d <<= 1) {
        int add = (t >= d) ? s[t - d] : 0;
        __syncthreads();
        s[t] += add;
        __syncthreads();
    }
    int off = (t == 0) ? 0 : s[t - 1];
#pragma unroll
    for (int k = 0; k < 4; ++k) {
        if (base + k < N) row_ptr[base + k] = off;
        off += v[k];
    }
    if (t == THREADS - 1) bsum[blockIdx.x] = s[THREADS - 1];
}

// Single-block exclusive scan of block sums (nb <= 256).
__global__ __launch_bounds__(THREADS) void scan2_kernel(int* __restrict__ bsum, int nb) {
    __shared__ int s[THREADS];
    int t = threadIdx.x;
    s[t] = (t < nb) ? bsum[t] : 0;
    __syncthreads();
    for (int d = 1; d < THREADS; d <<= 1) {
        int add = (t >= d) ? s[t - d] : 0;
        __syncthreads();
        s[t] += add;
        __syncthreads();
    }
    if (t < nb) bsum[t] = (t == 0) ? 0 : s[t - 1];
}

__global__ __launch_bounds__(THREADS) void scan3_kernel(int* __restrict__ row_ptr,
                                                        const int* __restrict__ bsum,
                                                        int* __restrict__ cursor, int N) {
    int i = blockIdx.x * THREADS + threadIdx.x;
    if (i < N) {
        int r = row_ptr[i] + bsum[i >> 10];
        row_ptr[i] = r;
        cursor[i] = r;
    }
}

// entries[pos] = src | (embIdx << 17)   (src < 2^17, embIdx = bt*3+bd < 18)
__global__ __launch_bounds__(THREADS) void fill_kernel(const int* __restrict__ src,
                                                       const int* __restrict__ dst,
                                                       const int* __restrict__ attr,
                                                       int* __restrict__ cursor,
                                                       int* __restrict__ entries, int E) {
    int e = blockIdx.x * THREADS + threadIdx.x;
    if (e >= E) return;
    int s = src[e];
    int d = dst[e];
    int2 a = ((const int2*)attr)[e];
    int pos = atomicAdd(&cursor[d], 1);
    entries[pos] = s | ((a.x * 3 + a.y) << 17);
}

// H = X @ W.T + B. 4-wave blocks, 64-row tile; wave w owns cols [16w,16w+16).
// W/B reads wave-uniform -> scalar loads; stores staged via LDS (R3: 3.4x write-amp fix).
template <bool RELU_IN>
__global__ __launch_bounds__(THREADS) void gemm64_kernel(const float* __restrict__ X,
                                                         const float* __restrict__ W,
                                                         const float* __restrict__ B,
                                                         float* __restrict__ H, int N) {
    __shared__ float smem[64][68];
    int t = threadIdx.x;
    int lane = t & 63;
    int wave = __builtin_amdgcn_readfirstlane(t >> 6);
    int row = blockIdx.x * 64 + lane;

    const float* Wp = W + wave * (16 * 64);
    const float* Bp = B + wave * 16;

    float xr[64];
    if (row < N) {
        const float4* xp = (const float4*)(X + (size_t)row * 64);
#pragma unroll
        for (int m = 0; m < 16; ++m) {
            float4 v = xp[m];
            if (RELU_IN) {
                v.x = fmaxf(v.x, 0.0f);
                v.y = fmaxf(v.y, 0.0f);
                v.z = fmaxf(v.z, 0.0f);
                v.w = fmaxf(v.w, 0.0f);
            }
            xr[4 * m + 0] = v.x;
            xr[4 * m + 1] = v.y;
            xr[4 * m + 2] = v.z;
            xr[4 * m + 3] = v.w;
        }
    } else {
#pragma unroll
        for (int k = 0; k < 64; ++k) xr[k] = 0.0f;
    }

    float acc[16];
#pragma unroll
    for (int j = 0; j < 16; ++j) acc[j] = Bp[j];
#pragma unroll
    for (int k = 0; k < 64; ++k) {
        float xk = xr[k];
#pragma unroll
        for (int j = 0; j < 16; ++j) acc[j] = fmaf(xk, Wp[j * 64 + k], acc[j]);
    }

#pragma unroll
    for (int j4 = 0; j4 < 4; ++j4) {
        *(float4*)(&smem[lane][wave * 16 + j4 * 4]) =
            make_float4(acc[4 * j4], acc[4 * j4 + 1], acc[4 * j4 + 2], acc[4 * j4 + 3]);
    }
    __syncthreads();

#pragma unroll
    for (int i = 0; i < 4; ++i) {
        int idx = t + i * THREADS;
        int r = idx >> 4;
        int c = (idx & 15) << 2;
        int grow = blockIdx.x * 64 + r;
        if (grow < N) *(float4*)(H + (size_t)grow * 64 + c) = *(const float4*)(&smem[r][c]);
    }
}

// out[n] = dis[n]^2*(H[n]+embc[12]) + sum_k dis[s]*dis[n]*(H[s]+embc[ei])
// 16 threads/node, 4 dims each; edge loop unrolled 2-wide for gather MLP.
__global__ __launch_bounds__(THREADS) void aggregate_kernel(const float* __restrict__ H,
                                                            const float* __restrict__ disv,
                                                            const float* __restrict__ ebond,
                                                            const float* __restrict__ edir,
                                                            const int* __restrict__ row_ptr,
                                                            const int* __restrict__ cnt,
                                                            const int* __restrict__ entries,
                                                            float* __restrict__ out, int N) {
    __shared__ float embc[18][64];
    int t = threadIdx.x;
    for (int i = t; i < 18 * 64; i += THREADS) {
        int row = i >> 6, c = i & 63;
        embc[row][c] = ebond[(row / 3) * 64 + c] + edir[(row % 3) * 64 + c];
    }
    __syncthreads();

    int n = blockIdx.x * 16 + (t >> 4);
    if (n >= N) return;
    int c = (t & 15) << 2;

    float dn = disv[n];
    float4 hv = *(const float4*)(H + (size_t)n * 64 + c);
    float4 em = *(const float4*)(&embc[12][c]);  // self-loop: bt=4, bd=0 -> idx 12
    float nrm = dn * dn;
    float4 acc0, acc1;
    acc0.x = nrm * (hv.x + em.x);
    acc0.y = nrm * (hv.y + em.y);
    acc0.z = nrm * (hv.z + em.z);
    acc0.w = nrm * (hv.w + em.w);
    acc1 = make_float4(0.0f, 0.0f, 0.0f, 0.0f);

    int p = row_ptr[n];
    int end = p + cnt[n];
    for (; p + 1 < end; p += 2) {
        int u0 = entries[p];
        int u1 = entries[p + 1];
        int s0 = u0 & 0x1FFFF, e0 = u0 >> 17;
        int s1 = u1 & 0x1FFFF, e1 = u1 >> 17;
        float w0 = disv[s0] * dn;
        float w1 = disv[s1] * dn;
        float4 h0 = *(const float4*)(H + (size_t)s0 * 64 + c);
        float4 h1 = *(const float4*)(H + (size_t)s1 * 64 + c);
        float4 b0 = *(const float4*)(&embc[e0][c]);
        float4 b1 = *(const float4*)(&embc[e1][c]);
        acc0.x = fmaf(w0, h0.x + b0.x, acc0.x);
        acc0.y = fmaf(w0, h0.y + b0.y, acc0.y);
        acc0.z = fmaf(w0, h0.z + b0.z, acc0.z);
        acc0.w = fmaf(w0, h0.w + b0.w, acc0.w);
        acc1.x = fmaf(w1, h1.x + b1.x, acc1.x);
        acc1.y = fmaf(w1, h1.y + b1.y, acc1.y);
        acc1.z = fmaf(w1, h1.z + b1.z, acc1.z);
        acc1.w = fmaf(w1, h1.w + b1.w, acc1.w);
    }
    if (p < end) {
        int u0 = entries[p];
        int s0 = u0 & 0x1FFFF, e0 = u0 >> 17;
        float w0 = disv[s0] * dn;
        float4 h0 = *(const float4*)(H + (size_t)s0 * 64 + c);
        float4 b0 = *(const float4*)(&embc[e0][c]);
        acc0.x = fmaf(w0, h0.x + b0.x, acc0.x);
        acc0.y = fmaf(w0, h0.y + b0.y, acc0.y);
        acc0.z = fmaf(w0, h0.z + b0.z, acc0.z);
        acc0.w = fmaf(w0, h0.w + b0.w, acc0.w);
    }
    acc0.x += acc1.x;
    acc0.y += acc1.y;
    acc0.z += acc1.z;
    acc0.w += acc1.w;
    *(float4*)(out + (size_t)n * 64 + c) = acc0;
}

extern "C" void kernel_launch(void* const* d_in, const int* in_sizes, int n_in,
                              void* d_out, int out_size, void* d_ws, size_t ws_size,
                              hipStream_t stream) {
    const float* x      = (const float*)d_in[0];
    const int*   eidx   = (const int*)d_in[1];
    const int*   eattr  = (const int*)d_in[2];
    const float* W1     = (const float*)d_in[3];
    const float* b1     = (const float*)d_in[4];
    const float* ebond1 = (const float*)d_in[5];
    const float* edir1  = (const float*)d_in[6];
    const float* W2     = (const float*)d_in[7];
    const float* b2     = (const float*)d_in[8];
    const float* ebond2 = (const float*)d_in[9];
    const float* edir2  = (const float*)d_in[10];

    const int N = in_sizes[0] / 64;
    const int E = in_sizes[1] / 2;
    const int* src = eidx;
    const int* dst = eidx + E;
    float* out = (float*)d_out;

    // Workspace (~37.6 MB)
    char* w = (char*)d_ws;
    size_t Na = ((size_t)N * 4 + 255) & ~(size_t)255;
    size_t Ea = ((size_t)E * 4 + 255) & ~(size_t)255;
    const int strideI = (int)(Na / 4);
    float* disv    = (float*)w;  w += Na;
    int*   srcdeg8 = (int*)w;    w += Na * NREP;  // 3.2 MB
    int*   dstcnt8 = (int*)w;    w += Na * NREP;  // 3.2 MB
    int*   dst_cnt = (int*)w;    w += Na;
    int*   row_ptr = (int*)w;    w += Na;
    int*   cursor  = (int*)w;    w += Na;
    int*   bsum    = (int*)w;    w += 4096;
    int*   entries = (int*)w;    w += Ea;                  // 4 MB
    float* bufA    = (float*)w;  w += (size_t)N * 64 * 4;  // 25.6 MB

    const int gN   = (N + THREADS - 1) / THREADS;
    const int gE   = (E + THREADS - 1) / THREADS;
    const int gG   = (N + 63) / 64;   // gemm tiles
    const int gN16 = (N + 15) / 16;   // aggregate: 16 nodes/block
    const int nb   = (N + 1023) / 1024;
    const int nZ   = strideI * NREP * 2;

    // CSR build (graph shared by both layers)
    zero_kernel<<<(nZ + THREADS - 1) / THREADS, THREADS, 0, stream>>>(srcdeg8, nZ);
    histogram8_kernel<<<gE, THREADS, 0, stream>>>(src, dst, srcdeg8, dstcnt8, strideI, E);
    reduce8_kernel<<<gN, THREADS, 0, stream>>>(srcdeg8, dstcnt8, disv, dst_cnt, strideI, N);
    scan1_kernel<<<nb, THREADS, 0, stream>>>(dst_cnt, row_ptr, bsum, N);
    scan2_kernel<<<1, THREADS, 0, stream>>>(bsum, nb);
    scan3_kernel<<<gN, THREADS, 0, stream>>>(row_ptr, bsum, cursor, N);
    fill_kernel<<<gE, THREADS, 0, stream>>>(src, dst, eattr, cursor, entries, E);

    // layer 1: h -> bufA, aggregate -> d_out (temp)
    gemm64_kernel<false><<<gG, THREADS, 0, stream>>>(x, W1, b1, bufA, N);
    aggregate_kernel<<<gN16, THREADS, 0, stream>>>(bufA, disv, ebond1, edir1, row_ptr, dst_cnt,
                                                   entries, out, N);

    // layer 2 (ReLU fused into GEMM input read): out -> bufA -> out
    gemm64_kernel<true><<<gG, THREADS, 0, stream>>>(out, W2, b2, bufA, N);
    aggregate_kernel<<<gN16, THREADS, 0, stream>>>(bufA, disv, ebond2, edir2, row_ptr, dst_cnt,
                                                   entries, out, N);
}

// Round 7
// 339.204 us; speedup vs baseline: 3.1991x; 1.1989x over previous
//
#include <hip/hip_runtime.h>

// GCN 2-layer forward (Hu et al. mol-GNN variant), fp32 — atomic-free CSR build.
//
//   dis[n] = 1/sqrt(1 + outdeg(n))
//   per layer: h = X@W.T + b
//              out[n] = dis[n]^2*(h[n]+emb_self) + sum_{e: dst=n} dis[s]*dis[n]*(h[s]+emb_e)
//   ReLU fused into GEMM2 input read.
//
// Measured facts driving this design:
//  - R4/R6: device-scope random global atomics run at ~26 G ops/s as memory-side
//    RMW (WRITE_SIZE ~32B/op) regardless of x8 replication -> eliminate, don't tune.
//  - R5: bucket partition kernels were correct; the regression was its aggregate
//    (stride-68 LDS acc = guaranteed 8-way bank conflicts + 782-block grid).
//    Keep R6's CSR aggregate (2-wide unroll) verbatim.
// Build: two-level counting sort by dst (512 chunk-blocks -> per-(bucket,block)
// counts -> scans -> LDS-cursor placement -> per-bucket sort by node), all LDS
// atomics only. Same machinery (byte payload) counts src out-degrees for dis.
// Workspace ~40 MB (proven-safe budget: R1's 51.6 MB passed, R2's 61.2 MB overflowed).

#define THREADS 256
#define PB 512      // partition chunk-blocks
#define MAXNB 1024  // max 128-node buckets (N <= 131072)

// ---- P1: per-(bucket,block) histograms over src- and dst-buckets ----
__global__ __launch_bounds__(THREADS) void part_count_kernel(
    const int* __restrict__ src, const int* __restrict__ dst,
    int* __restrict__ countsS, int* __restrict__ countsD,  // [NB*PB] bucket-major
    int E, int NB) {
    __shared__ int hS[MAXNB], hD[MAXNB];
    int t = threadIdx.x, b = blockIdx.x;
    for (int k = t; k < NB; k += THREADS) { hS[k] = 0; hD[k] = 0; }
    __syncthreads();
    int chunk = (E + PB - 1) / PB;
    int lo = b * chunk, hi = min(E, lo + chunk);
    for (int i = lo + t; i < hi; i += THREADS) {
        atomicAdd(&hS[src[i] >> 7], 1);  // LDS atomic
        atomicAdd(&hD[dst[i] >> 7], 1);  // LDS atomic
    }
    __syncthreads();
    for (int k = t; k < NB; k += THREADS) {
        countsS[k * PB + b] = hS[k];
        countsD[k * PB + b] = hD[k];
    }
}

// ---- P2a: per-bucket exclusive scan over the PB per-block counts (in place) ----
__global__ __launch_bounds__(THREADS) void part_scanblocks_kernel(
    int* __restrict__ countsS, int* __restrict__ countsD,
    int* __restrict__ totalS, int* __restrict__ totalD) {
    __shared__ int s[THREADS];
    int t = threadIdx.x, k = blockIdx.x;
#pragma unroll 1
    for (int pass = 0; pass < 2; ++pass) {
        int* cp = pass ? countsD : countsS;
        int* tp = pass ? totalD : totalS;
        int base = k * PB + t * 2;
        int v0 = cp[base], v1 = cp[base + 1];
        s[t] = v0 + v1;
        __syncthreads();
        for (int d = 1; d < THREADS; d <<= 1) {
            int a = (t >= d) ? s[t - d] : 0;
            __syncthreads();
            s[t] += a;
            __syncthreads();
        }
        int off = (t == 0) ? 0 : s[t - 1];
        cp[base] = off;
        cp[base + 1] = off + v0;
        if (t == THREADS - 1) tp[k] = s[t];
        __syncthreads();
    }
}

// ---- P2b: exclusive scan of bucket totals -> bucket base offsets (NB <= 1024) ----
__global__ __launch_bounds__(THREADS) void part_scanbase_kernel(
    const int* __restrict__ totalS, const int* __restrict__ totalD,
    int* __restrict__ baseS, int* __restrict__ baseD, int NB) {
    __shared__ int s[THREADS];
    int t = threadIdx.x;
#pragma unroll 1
    for (int pass = 0; pass < 2; ++pass) {
        const int* in = pass ? totalD : totalS;
        int* out = pass ? baseD : baseS;
        int base = t * 4;
        int v[4];
#pragma unroll
        for (int k = 0; k < 4; ++k) v[k] = (base + k < NB) ? in[base + k] : 0;
        s[t] = v[0] + v[1] + v[2] + v[3];
        __syncthreads();
        for (int d = 1; d < THREADS; d <<= 1) {
            int a = (t >= d) ? s[t - d] : 0;
            __syncthreads();
            s[t] += a;
            __syncthreads();
        }
        int off = (t == 0) ? 0 : s[t - 1];
#pragma unroll
        for (int k = 0; k < 4; ++k) {
            if (base + k < NB) out[base + k] = off;
            off += v[k];
        }
        __syncthreads();
    }
}

// ---- P3: placement (same chunking as P1), LDS cursors, plain stores ----
// payD[pos] = src | emb<<17 | dstLow7<<22 ; payS[pos] = srcLow7 (byte)
__global__ __launch_bounds__(THREADS) void part_scatter_kernel(
    const int* __restrict__ src, const int* __restrict__ dst, const int* __restrict__ attr,
    const int* __restrict__ countsS, const int* __restrict__ countsD,
    const int* __restrict__ baseS, const int* __restrict__ baseD,
    unsigned char* __restrict__ payS, int* __restrict__ payD, int E, int NB) {
    __shared__ int curS[MAXNB], curD[MAXNB];
    int t = threadIdx.x, b = blockIdx.x;
    for (int k = t; k < NB; k += THREADS) {
        curS[k] = baseS[k] + countsS[k * PB + b];
        curD[k] = baseD[k] + countsD[k * PB + b];
    }
    __syncthreads();
    int chunk = (E + PB - 1) / PB;
    int lo = b * chunk, hi = min(E, lo + chunk);
    const int2* ap = (const int2*)attr;
    for (int i = lo + t; i < hi; i += THREADS) {
        int sv = src[i], dv = dst[i];
        int2 a = ap[i];
        int pS = atomicAdd(&curS[sv >> 7], 1);  // LDS atomic
        payS[pS] = (unsigned char)(sv & 127);
        int pD = atomicAdd(&curD[dv >> 7], 1);  // LDS atomic
        payD[pD] = sv | ((a.x * 3 + a.y) << 17) | ((dv & 127) << 22);
    }
}

// ---- P4: out-degree per node from src-grouped bytes -> dis ----
__global__ __launch_bounds__(THREADS) void deg_dis_kernel(
    const unsigned char* __restrict__ payS, const int* __restrict__ baseS,
    const int* __restrict__ totalS, float* __restrict__ disv, int N) {
    __shared__ int cnt[128];
    int t = threadIdx.x, k = blockIdx.x;
    if (t < 128) cnt[t] = 0;
    __syncthreads();
    int off = baseS[k], n = totalS[k];
    for (int i = t; i < n; i += THREADS) atomicAdd(&cnt[payS[off + i]], 1);  // LDS atomic
    __syncthreads();
    if (t < 128) {
        int node = k * 128 + t;
        if (node < N) disv[node] = 1.0f / sqrtf(1.0f + (float)cnt[t]);
    }
}

// ---- P5: per-bucket counting sort by node -> sorted entries + per-node row_ptr/cnt ----
__global__ __launch_bounds__(THREADS) void sort_bucket_kernel(
    const int* __restrict__ payD, const int* __restrict__ baseD,
    const int* __restrict__ totalD, int* __restrict__ sorted,
    int* __restrict__ row_ptr, int* __restrict__ cnt_out, int N) {
    __shared__ int cnt[128], off[128], cur[128];
    int t = threadIdx.x, k = blockIdx.x;
    if (t < 128) cnt[t] = 0;
    __syncthreads();
    int eoff = baseD[k], ecnt = totalD[k];
    for (int i = t; i < ecnt; i += THREADS)
        atomicAdd(&cnt[(payD[eoff + i] >> 22) & 127], 1);  // LDS atomic
    __syncthreads();
    // inclusive scan of cnt[0..127] (first 128 threads), then exclusive offsets
    __shared__ int sc[128];
    if (t < 128) sc[t] = cnt[t];
    __syncthreads();
    for (int d = 1; d < 128; d <<= 1) {
        int a = (t < 128 && t >= d) ? sc[t - d] : 0;
        __syncthreads();
        if (t < 128) sc[t] += a;
        __syncthreads();
    }
    if (t < 128) {
        int o = (t == 0) ? 0 : sc[t - 1];
        off[t] = o;
        cur[t] = o;
        int node = k * 128 + t;
        if (node < N) {
            row_ptr[node] = eoff + o;
            cnt_out[node] = cnt[t];
        }
    }
    __syncthreads();
    for (int i = t; i < ecnt; i += THREADS) {
        int u = payD[eoff + i];
        int dl = (u >> 22) & 127;
        int p = atomicAdd(&cur[dl], 1);  // LDS atomic
        sorted[eoff + p] = u & 0x3FFFFF;  // strip dst bits: src | emb<<17
    }
}

// ---- GEMM: H = X @ W.T + B. 4-wave blocks, 64-row tile; wave w owns cols [16w,16w+16).
// W/B reads wave-uniform -> scalar loads; stores staged via LDS (R3: 3.4x write-amp fix).
template <bool RELU_IN>
__global__ __launch_bounds__(THREADS) void gemm64_kernel(const float* __restrict__ X,
                                                         const float* __restrict__ W,
                                                         const float* __restrict__ B,
                                                         float* __restrict__ H, int N) {
    __shared__ float smem[64][68];
    int t = threadIdx.x;
    int lane = t & 63;
    int wave = __builtin_amdgcn_readfirstlane(t >> 6);
    int row = blockIdx.x * 64 + lane;

    const float* Wp = W + wave * (16 * 64);
    const float* Bp = B + wave * 16;

    float xr[64];
    if (row < N) {
        const float4* xp = (const float4*)(X + (size_t)row * 64);
#pragma unroll
        for (int m = 0; m < 16; ++m) {
            float4 v = xp[m];
            if (RELU_IN) {
                v.x = fmaxf(v.x, 0.0f);
                v.y = fmaxf(v.y, 0.0f);
                v.z = fmaxf(v.z, 0.0f);
                v.w = fmaxf(v.w, 0.0f);
            }
            xr[4 * m + 0] = v.x;
            xr[4 * m + 1] = v.y;
            xr[4 * m + 2] = v.z;
            xr[4 * m + 3] = v.w;
        }
    } else {
#pragma unroll
        for (int k = 0; k < 64; ++k) xr[k] = 0.0f;
    }

    float acc[16];
#pragma unroll
    for (int j = 0; j < 16; ++j) acc[j] = Bp[j];
#pragma unroll
    for (int k = 0; k < 64; ++k) {
        float xk = xr[k];
#pragma unroll
        for (int j = 0; j < 16; ++j) acc[j] = fmaf(xk, Wp[j * 64 + k], acc[j]);
    }

#pragma unroll
    for (int j4 = 0; j4 < 4; ++j4) {
        *(float4*)(&smem[lane][wave * 16 + j4 * 4]) =
            make_float4(acc[4 * j4], acc[4 * j4 + 1], acc[4 * j4 + 2], acc[4 * j4 + 3]);
    }
    __syncthreads();

#pragma unroll
    for (int i = 0; i < 4; ++i) {
        int idx = t + i * THREADS;
        int r = idx >> 4;
        int c = (idx & 15) << 2;
        int grow = blockIdx.x * 64 + r;
        if (grow < N) *(float4*)(H + (size_t)grow * 64 + c) = *(const float4*)(&smem[r][c]);
    }
}

// out[n] = dis[n]^2*(H[n]+embc[12]) + sum_k dis[s]*dis[n]*(H[s]+embc[ei])
// 16 threads/node, 4 dims each; edge loop unrolled 2-wide for gather MLP. (R6-proven.)
__global__ __launch_bounds__(THREADS) void aggregate_kernel(const float* __restrict__ H,
                                                            const float* __restrict__ disv,
                                                            const float* __restrict__ ebond,
                                                            const float* __restrict__ edir,
                                                            const int* __restrict__ row_ptr,
                                                            const int* __restrict__ cnt,
                                                            const int* __restrict__ entries,
                                                            float* __restrict__ out, int N) {
    __shared__ float embc[18][64];
    int t = threadIdx.x;
    for (int i = t; i < 18 * 64; i += THREADS) {
        int row = i >> 6, c = i & 63;
        embc[row][c] = ebond[(row / 3) * 64 + c] + edir[(row % 3) * 64 + c];
    }
    __syncthreads();

    int n = blockIdx.x * 16 + (t >> 4);
    if (n >= N) return;
    int c = (t & 15) << 2;

    float dn = disv[n];
    float4 hv = *(const float4*)(H + (size_t)n * 64 + c);
    float4 em = *(const float4*)(&embc[12][c]);  // self-loop: bt=4, bd=0 -> idx 12
    float nrm = dn * dn;
    float4 acc0, acc1;
    acc0.x = nrm * (hv.x + em.x);
    acc0.y = nrm * (hv.y + em.y);
    acc0.z = nrm * (hv.z + em.z);
    acc0.w = nrm * (hv.w + em.w);
    acc1 = make_float4(0.0f, 0.0f, 0.0f, 0.0f);

    int p = row_ptr[n];
    int end = p + cnt[n];
    for (; p + 1 < end; p += 2) {
        int u0 = entries[p];
        int u1 = entries[p + 1];
        int s0 = u0 & 0x1FFFF, e0 = u0 >> 17;
        int s1 = u1 & 0x1FFFF, e1 = u1 >> 17;
        float w0 = disv[s0] * dn;
        float w1 = disv[s1] * dn;
        float4 h0 = *(const float4*)(H + (size_t)s0 * 64 + c);
        float4 h1 = *(const float4*)(H + (size_t)s1 * 64 + c);
        float4 b0 = *(const float4*)(&embc[e0][c]);
        float4 b1 = *(const float4*)(&embc[e1][c]);
        acc0.x = fmaf(w0, h0.x + b0.x, acc0.x);
        acc0.y = fmaf(w0, h0.y + b0.y, acc0.y);
        acc0.z = fmaf(w0, h0.z + b0.z, acc0.z);
        acc0.w = fmaf(w0, h0.w + b0.w, acc0.w);
        acc1.x = fmaf(w1, h1.x + b1.x, acc1.x);
        acc1.y = fmaf(w1, h1.y + b1.y, acc1.y);
        acc1.z = fmaf(w1, h1.z + b1.z, acc1.z);
        acc1.w = fmaf(w1, h1.w + b1.w, acc1.w);
    }
    if (p < end) {
        int u0 = entries[p];
        int s0 = u0 & 0x1FFFF, e0 = u0 >> 17;
        float w0 = disv[s0] * dn;
        float4 h0 = *(const float4*)(H + (size_t)s0 * 64 + c);
        float4 b0 = *(const float4*)(&embc[e0][c]);
        acc0.x = fmaf(w0, h0.x + b0.x, acc0.x);
        acc0.y = fmaf(w0, h0.y + b0.y, acc0.y);
        acc0.z = fmaf(w0, h0.z + b0.z, acc0.z);
        acc0.w = fmaf(w0, h0.w + b0.w, acc0.w);
    }
    acc0.x += acc1.x;
    acc0.y += acc1.y;
    acc0.z += acc1.z;
    acc0.w += acc1.w;
    *(float4*)(out + (size_t)n * 64 + c) = acc0;
}

extern "C" void kernel_launch(void* const* d_in, const int* in_sizes, int n_in,
                              void* d_out, int out_size, void* d_ws, size_t ws_size,
                              hipStream_t stream) {
    const float* x      = (const float*)d_in[0];
    const int*   eidx   = (const int*)d_in[1];
    const int*   eattr  = (const int*)d_in[2];
    const float* W1     = (const float*)d_in[3];
    const float* b1     = (const float*)d_in[4];
    const float* ebond1 = (const float*)d_in[5];
    const float* edir1  = (const float*)d_in[6];
    const float* W2     = (const float*)d_in[7];
    const float* b2     = (const float*)d_in[8];
    const float* ebond2 = (const float*)d_in[9];
    const float* edir2  = (const float*)d_in[10];

    const int N = in_sizes[0] / 64;
    const int E = in_sizes[1] / 2;
    const int* src = eidx;
    const int* dst = eidx + E;
    float* out = (float*)d_out;
    const int NB = (N + 127) / 128;

    // Workspace (~40 MB; proven-safe < 51.6 MB)
    char* w = (char*)d_ws;
    size_t Na = ((size_t)N * 4 + 255) & ~(size_t)255;
    size_t Ea = ((size_t)E * 4 + 255) & ~(size_t)255;
    float* disv    = (float*)w;          w += Na;
    int*   row_ptr = (int*)w;            w += Na;
    int*   cnt     = (int*)w;            w += Na;
    int*   countsS = (int*)w;            w += (size_t)MAXNB * PB * 4;  // 2 MB
    int*   countsD = (int*)w;            w += (size_t)MAXNB * PB * 4;  // 2 MB
    int*   totalS  = (int*)w;            w += MAXNB * 4;
    int*   totalD  = (int*)w;            w += MAXNB * 4;
    int*   baseS   = (int*)w;            w += MAXNB * 4;
    int*   baseD   = (int*)w;            w += MAXNB * 4;
    int*   payD    = (int*)w;            w += Ea;                      // 4 MB
    int*   sorted  = (int*)w;            w += Ea;                      // 4 MB
    unsigned char* payS = (unsigned char*)w;  w += (Ea / 4 + 256);     // 1 MB
    float* bufA    = (float*)w;          w += (size_t)N * 64 * 4;      // 25.6 MB

    const int gG   = (N + 63) / 64;   // gemm tiles
    const int gN16 = (N + 15) / 16;   // aggregate: 16 nodes/block

    // Atomic-free CSR build (graph shared by both layers)
    part_count_kernel<<<PB, THREADS, 0, stream>>>(src, dst, countsS, countsD, E, NB);
    part_scanblocks_kernel<<<NB, THREADS, 0, stream>>>(countsS, countsD, totalS, totalD);
    part_scanbase_kernel<<<1, THREADS, 0, stream>>>(totalS, totalD, baseS, baseD, NB);
    part_scatter_kernel<<<PB, THREADS, 0, stream>>>(src, dst, eattr, countsS, countsD, baseS,
                                                    baseD, payS, payD, E, NB);
    deg_dis_kernel<<<NB, THREADS, 0, stream>>>(payS, baseS, totalS, disv, N);
    sort_bucket_kernel<<<NB, THREADS, 0, stream>>>(payD, baseD, totalD, sorted, row_ptr, cnt, N);

    // layer 1: h -> bufA, aggregate -> d_out (temp)
    gemm64_kernel<false><<<gG, THREADS, 0, stream>>>(x, W1, b1, bufA, N);
    aggregate_kernel<<<gN16, THREADS, 0, stream>>>(bufA, disv, ebond1, edir1, row_ptr, cnt,
                                                   sorted, out, N);

    // layer 2 (ReLU fused into GEMM input read): out -> bufA -> out
    gemm64_kernel<true><<<gG, THREADS, 0, stream>>>(out, W2, b2, bufA, N);
    aggregate_kernel<<<gN16, THREADS, 0, stream>>>(bufA, disv, ebond2, edir2, row_ptr, cnt,
                                                   sorted, out, N);
}

// Round 8
// 305.953 us; speedup vs baseline: 3.5468x; 1.1087x over previous
//
#include <hip/hip_runtime.h>

// GCN 2-layer forward (Hu et al. mol-GNN variant) — atomic-free CSR build, bf16 H gather.
//
//   dis[n] = 1/sqrt(1 + outdeg(n))
//   per layer: h = X@W.T + b   (stored bf16: gather traffic is the measured bottleneck)
//              out[n] = dis[n]^2*(h[n]+emb_self) + sum_{e: dst=n} dis[s]*dis[n]*(h[s]+emb_e)
//   ReLU fused into GEMM2 input read. Aggregate outputs stay fp32.
//
// Measured facts driving this design:
//  - R4/R6: device-scope random global atomics ~26 G ops/s memory-side RMW -> eliminated.
//  - R7: aggregate is BW-bound (3.5 TB/s, FETCH 181 MB vs 256 MB logical H-gather)
//    -> bf16 H halves gather bytes. Predicted absmax ~0.02-0.03 (threshold 0.0519).
//  - R7: part_scatter writes ~2.5 edges per 64B line (782 buckets x 512 blocks) -> ~6x
//    write amp. Coarse 1024-node buckets (98) give ~20-edge (80 B) windows -> ~1.5x.
// Payload: src(17b) | emb(5b)<<17 | dstLow10(10b)<<22  (unsigned, exactly 32 bits).
// Workspace ~25 MB (proven-safe: R1's 51.6 MB passed; R2's 61.2 MB overflowed).

#define THREADS 256
#define PB 512     // partition chunk-blocks
#define MAXNBC 128 // max 1024-node coarse buckets (N <= 131072)

__device__ __forceinline__ float bf2f(unsigned short v) {
    return __uint_as_float(((unsigned int)v) << 16);
}
__device__ __forceinline__ unsigned short f2bf(float f) {  // round-to-nearest-even
    unsigned int u = __float_as_uint(f);
    return (unsigned short)((u + 0x7FFFu + ((u >> 16) & 1u)) >> 16);
}

// ---- P1: per-(bucket,block) histograms over src- and dst- coarse buckets ----
__global__ __launch_bounds__(THREADS) void part_count_kernel(
    const int* __restrict__ src, const int* __restrict__ dst,
    int* __restrict__ countsS, int* __restrict__ countsD,  // [NBC*PB] bucket-major
    int E, int NBC) {
    __shared__ int hS[MAXNBC], hD[MAXNBC];
    int t = threadIdx.x, b = blockIdx.x;
    for (int k = t; k < NBC; k += THREADS) { hS[k] = 0; hD[k] = 0; }
    __syncthreads();
    int chunk = (E + PB - 1) / PB;
    int lo = b * chunk, hi = min(E, lo + chunk);
    for (int i = lo + t; i < hi; i += THREADS) {
        atomicAdd(&hS[src[i] >> 10], 1);  // LDS atomic
        atomicAdd(&hD[dst[i] >> 10], 1);  // LDS atomic
    }
    __syncthreads();
    for (int k = t; k < NBC; k += THREADS) {
        countsS[k * PB + b] = hS[k];
        countsD[k * PB + b] = hD[k];
    }
}

// ---- P2a: per-bucket exclusive scan over the PB per-block counts (in place) ----
__global__ __launch_bounds__(THREADS) void part_scanblocks_kernel(
    int* __restrict__ countsS, int* __restrict__ countsD,
    int* __restrict__ totalS, int* __restrict__ totalD) {
    __shared__ int s[THREADS];
    int t = threadIdx.x, k = blockIdx.x;
#pragma unroll 1
    for (int pass = 0; pass < 2; ++pass) {
        int* cp = pass ? countsD : countsS;
        int* tp = pass ? totalD : totalS;
        int base = k * PB + t * 2;
        int v0 = cp[base], v1 = cp[base + 1];
        s[t] = v0 + v1;
        __syncthreads();
        for (int d = 1; d < THREADS; d <<= 1) {
            int a = (t >= d) ? s[t - d] : 0;
            __syncthreads();
            s[t] += a;
            __syncthreads();
        }
        int off = (t == 0) ? 0 : s[t - 1];
        cp[base] = off;
        cp[base + 1] = off + v0;
        if (t == THREADS - 1) tp[k] = s[t];
        __syncthreads();
    }
}

// ---- P2b: exclusive scan of bucket totals -> bucket base offsets (NBC <= 128) ----
__global__ __launch_bounds__(THREADS) void part_scanbase_kernel(
    const int* __restrict__ totalS, const int* __restrict__ totalD,
    int* __restrict__ baseS, int* __restrict__ baseD, int NBC) {
    __shared__ int s[THREADS];
    int t = threadIdx.x;
#pragma unroll 1
    for (int pass = 0; pass < 2; ++pass) {
        const int* in = pass ? totalD : totalS;
        int* out = pass ? baseD : baseS;
        int v = (t < NBC) ? in[t] : 0;
        s[t] = v;
        __syncthreads();
        for (int d = 1; d < THREADS; d <<= 1) {
            int a = (t >= d) ? s[t - d] : 0;
            __syncthreads();
            s[t] += a;
            __syncthreads();
        }
        if (t < NBC) out[t] = s[t] - v;
        __syncthreads();
    }
}

// ---- P3: placement (same chunking as P1), LDS cursors, plain stores ----
__global__ __launch_bounds__(THREADS) void part_scatter_kernel(
    const int* __restrict__ src, const int* __restrict__ dst, const int* __restrict__ attr,
    const int* __restrict__ countsS, const int* __restrict__ countsD,
    const int* __restrict__ baseS, const int* __restrict__ baseD,
    unsigned short* __restrict__ payS, unsigned int* __restrict__ payD, int E, int NBC) {
    __shared__ int curS[MAXNBC], curD[MAXNBC];
    int t = threadIdx.x, b = blockIdx.x;
    for (int k = t; k < NBC; k += THREADS) {
        curS[k] = baseS[k] + countsS[k * PB + b];
        curD[k] = baseD[k] + countsD[k * PB + b];
    }
    __syncthreads();
    int chunk = (E + PB - 1) / PB;
    int lo = b * chunk, hi = min(E, lo + chunk);
    const int2* ap = (const int2*)attr;
    for (int i = lo + t; i < hi; i += THREADS) {
        int sv = src[i], dv = dst[i];
        int2 a = ap[i];
        int pS = atomicAdd(&curS[sv >> 10], 1);  // LDS atomic
        payS[pS] = (unsigned short)(sv & 1023);
        int pD = atomicAdd(&curD[dv >> 10], 1);  // LDS atomic
        payD[pD] = (unsigned int)sv | ((unsigned int)(a.x * 3 + a.y) << 17) |
                   ((unsigned int)(dv & 1023) << 22);
    }
}

// ---- P4: out-degree per node from src-grouped shorts -> dis ----
__global__ __launch_bounds__(THREADS) void deg_dis_kernel(
    const unsigned short* __restrict__ payS, const int* __restrict__ baseS,
    const int* __restrict__ totalS, float* __restrict__ disv, int N) {
    __shared__ int cnt[1024];
    int t = threadIdx.x, k = blockIdx.x;
    for (int i = t; i < 1024; i += THREADS) cnt[i] = 0;
    __syncthreads();
    int off = baseS[k], n = totalS[k];
    for (int i = t; i < n; i += THREADS) atomicAdd(&cnt[payS[off + i]], 1);  // LDS atomic
    __syncthreads();
    for (int i = t; i < 1024; i += THREADS) {
        int node = k * 1024 + i;
        if (node < N) disv[node] = 1.0f / sqrtf(1.0f + (float)cnt[i]);
    }
}

// ---- P5: per-bucket counting sort by node -> sorted entries + per-node row_ptr/cnt ----
__global__ __launch_bounds__(THREADS) void sort_bucket_kernel(
    const unsigned int* __restrict__ payD, const int* __restrict__ baseD,
    const int* __restrict__ totalD, unsigned int* __restrict__ sorted,
    int* __restrict__ row_ptr, int* __restrict__ cnt_out, int N) {
    __shared__ int cnt[1024], cur[1024];
    __shared__ int s[THREADS];
    int t = threadIdx.x, k = blockIdx.x;
    for (int i = t; i < 1024; i += THREADS) cnt[i] = 0;
    __syncthreads();
    int eoff = baseD[k], ecnt = totalD[k];
    for (int i = t; i < ecnt; i += THREADS)
        atomicAdd(&cnt[payD[eoff + i] >> 22], 1);  // LDS atomic
    __syncthreads();
    // exclusive scan of 1024 counts: 4/thread local sum -> block scan -> offsets
    int base4 = t * 4;
    int v0 = cnt[base4], v1 = cnt[base4 + 1], v2 = cnt[base4 + 2], v3 = cnt[base4 + 3];
    s[t] = v0 + v1 + v2 + v3;
    __syncthreads();
    for (int d = 1; d < THREADS; d <<= 1) {
        int a = (t >= d) ? s[t - d] : 0;
        __syncthreads();
        s[t] += a;
        __syncthreads();
    }
    int off = (t == 0) ? 0 : s[t - 1];
    int o0 = off, o1 = off + v0, o2 = o1 + v1, o3 = o2 + v2;
    __syncthreads();
    cur[base4] = o0;
    cur[base4 + 1] = o1;
    cur[base4 + 2] = o2;
    cur[base4 + 3] = o3;
#pragma unroll
    for (int j = 0; j < 4; ++j) {
        int node = k * 1024 + base4 + j;
        if (node < N) {
            row_ptr[node] = eoff + ((j == 0) ? o0 : (j == 1) ? o1 : (j == 2) ? o2 : o3);
            cnt_out[node] = (j == 0) ? v0 : (j == 1) ? v1 : (j == 2) ? v2 : v3;
        }
    }
    __syncthreads();
    for (int i = t; i < ecnt; i += THREADS) {
        unsigned int u = payD[eoff + i];
        int p = atomicAdd(&cur[u >> 22], 1);  // LDS atomic
        sorted[eoff + p] = u & 0x3FFFFFu;     // keep src | emb<<17
    }
}

// ---- GEMM: Hb = bf16(X @ W.T + B). 4-wave blocks, 64-row tile; wave w owns cols
// [16w,16w+16). W/B reads wave-uniform -> scalar loads; stores staged via LDS.
template <bool RELU_IN>
__global__ __launch_bounds__(THREADS) void gemm64_kernel(const float* __restrict__ X,
                                                         const float* __restrict__ W,
                                                         const float* __restrict__ B,
                                                         unsigned short* __restrict__ Hb,
                                                         int N) {
    __shared__ float smem[64][68];
    int t = threadIdx.x;
    int lane = t & 63;
    int wave = __builtin_amdgcn_readfirstlane(t >> 6);
    int row = blockIdx.x * 64 + lane;

    const float* Wp = W + wave * (16 * 64);
    const float* Bp = B + wave * 16;

    float xr[64];
    if (row < N) {
        const float4* xp = (const float4*)(X + (size_t)row * 64);
#pragma unroll
        for (int m = 0; m < 16; ++m) {
            float4 v = xp[m];
            if (RELU_IN) {
                v.x = fmaxf(v.x, 0.0f);
                v.y = fmaxf(v.y, 0.0f);
                v.z = fmaxf(v.z, 0.0f);
                v.w = fmaxf(v.w, 0.0f);
            }
            xr[4 * m + 0] = v.x;
            xr[4 * m + 1] = v.y;
            xr[4 * m + 2] = v.z;
            xr[4 * m + 3] = v.w;
        }
    } else {
#pragma unroll
        for (int k = 0; k < 64; ++k) xr[k] = 0.0f;
    }

    float acc[16];
#pragma unroll
    for (int j = 0; j < 16; ++j) acc[j] = Bp[j];
#pragma unroll
    for (int k = 0; k < 64; ++k) {
        float xk = xr[k];
#pragma unroll
        for (int j = 0; j < 16; ++j) acc[j] = fmaf(xk, Wp[j * 64 + k], acc[j]);
    }

#pragma unroll
    for (int j4 = 0; j4 < 4; ++j4) {
        *(float4*)(&smem[lane][wave * 16 + j4 * 4]) =
            make_float4(acc[4 * j4], acc[4 * j4 + 1], acc[4 * j4 + 2], acc[4 * j4 + 3]);
    }
    __syncthreads();

    // writeout: 512 groups of 8 floats -> 8 bf16 (16 B store); 2 groups/thread
#pragma unroll
    for (int i = 0; i < 2; ++i) {
        int idx = t + i * THREADS;
        int r = idx >> 3;
        int c8 = (idx & 7) << 3;
        int grow = blockIdx.x * 64 + r;
        if (grow < N) {
            ushort4 lo, hi2;
            lo.x = f2bf(smem[r][c8 + 0]);
            lo.y = f2bf(smem[r][c8 + 1]);
            lo.z = f2bf(smem[r][c8 + 2]);
            lo.w = f2bf(smem[r][c8 + 3]);
            hi2.x = f2bf(smem[r][c8 + 4]);
            hi2.y = f2bf(smem[r][c8 + 5]);
            hi2.z = f2bf(smem[r][c8 + 6]);
            hi2.w = f2bf(smem[r][c8 + 7]);
            ushort4* dstp = (ushort4*)(Hb + (size_t)grow * 64 + c8);
            dstp[0] = lo;
            dstp[1] = hi2;
        }
    }
}

// out[n] = dis[n]^2*(Hb[n]+embc[12]) + sum_k dis[s]*dis[n]*(Hb[s]+embc[ei])
// 16 threads/node, 4 dims each; edge loop unrolled 2-wide for gather MLP.
__global__ __launch_bounds__(THREADS) void aggregate_kernel(
    const unsigned short* __restrict__ Hb, const float* __restrict__ disv,
    const float* __restrict__ ebond, const float* __restrict__ edir,
    const int* __restrict__ row_ptr, const int* __restrict__ cnt,
    const unsigned int* __restrict__ entries, float* __restrict__ out, int N) {
    __shared__ float embc[18][64];
    int t = threadIdx.x;
    for (int i = t; i < 18 * 64; i += THREADS) {
        int row = i >> 6, c = i & 63;
        embc[row][c] = ebond[(row / 3) * 64 + c] + edir[(row % 3) * 64 + c];
    }
    __syncthreads();

    int n = blockIdx.x * 16 + (t >> 4);
    if (n >= N) return;
    int c = (t & 15) << 2;

    float dn = disv[n];
    ushort4 hu = *(const ushort4*)(Hb + (size_t)n * 64 + c);
    float4 em = *(const float4*)(&embc[12][c]);  // self-loop: bt=4, bd=0 -> idx 12
    float nrm = dn * dn;
    float4 acc0, acc1;
    acc0.x = nrm * (bf2f(hu.x) + em.x);
    acc0.y = nrm * (bf2f(hu.y) + em.y);
    acc0.z = nrm * (bf2f(hu.z) + em.z);
    acc0.w = nrm * (bf2f(hu.w) + em.w);
    acc1 = make_float4(0.0f, 0.0f, 0.0f, 0.0f);

    int p = row_ptr[n];
    int end = p + cnt[n];
    for (; p + 1 < end; p += 2) {
        unsigned int u0 = entries[p];
        unsigned int u1 = entries[p + 1];
        int s0 = u0 & 0x1FFFF, e0 = (u0 >> 17) & 31;
        int s1 = u1 & 0x1FFFF, e1 = (u1 >> 17) & 31;
        float w0 = disv[s0] * dn;
        float w1 = disv[s1] * dn;
        ushort4 h0 = *(const ushort4*)(Hb + (size_t)s0 * 64 + c);
        ushort4 h1 = *(const ushort4*)(Hb + (size_t)s1 * 64 + c);
        float4 b0 = *(const float4*)(&embc[e0][c]);
        float4 b1 = *(const float4*)(&embc[e1][c]);
        acc0.x = fmaf(w0, bf2f(h0.x) + b0.x, acc0.x);
        acc0.y = fmaf(w0, bf2f(h0.y) + b0.y, acc0.y);
        acc0.z = fmaf(w0, bf2f(h0.z) + b0.z, acc0.z);
        acc0.w = fmaf(w0, bf2f(h0.w) + b0.w, acc0.w);
        acc1.x = fmaf(w1, bf2f(h1.x) + b1.x, acc1.x);
        acc1.y = fmaf(w1, bf2f(h1.y) + b1.y, acc1.y);
        acc1.z = fmaf(w1, bf2f(h1.z) + b1.z, acc1.z);
        acc1.w = fmaf(w1, bf2f(h1.w) + b1.w, acc1.w);
    }
    if (p < end) {
        unsigned int u0 = entries[p];
        int s0 = u0 & 0x1FFFF, e0 = (u0 >> 17) & 31;
        float w0 = disv[s0] * dn;
        ushort4 h0 = *(const ushort4*)(Hb + (size_t)s0 * 64 + c);
        float4 b0 = *(const float4*)(&embc[e0][c]);
        acc0.x = fmaf(w0, bf2f(h0.x) + b0.x, acc0.x);
        acc0.y = fmaf(w0, bf2f(h0.y) + b0.y, acc0.y);
        acc0.z = fmaf(w0, bf2f(h0.z) + b0.z, acc0.z);
        acc0.w = fmaf(w0, bf2f(h0.w) + b0.w, acc0.w);
    }
    acc0.x += acc1.x;
    acc0.y += acc1.y;
    acc0.z += acc1.z;
    acc0.w += acc1.w;
    *(float4*)(out + (size_t)n * 64 + c) = acc0;
}

extern "C" void kernel_launch(void* const* d_in, const int* in_sizes, int n_in,
                              void* d_out, int out_size, void* d_ws, size_t ws_size,
                              hipStream_t stream) {
    const float* x      = (const float*)d_in[0];
    const int*   eidx   = (const int*)d_in[1];
    const int*   eattr  = (const int*)d_in[2];
    const float* W1     = (const float*)d_in[3];
    const float* b1     = (const float*)d_in[4];
    const float* ebond1 = (const float*)d_in[5];
    const float* edir1  = (const float*)d_in[6];
    const float* W2     = (const float*)d_in[7];
    const float* b2     = (const float*)d_in[8];
    const float* ebond2 = (const float*)d_in[9];
    const float* edir2  = (const float*)d_in[10];

    const int N = in_sizes[0] / 64;
    const int E = in_sizes[1] / 2;
    const int* src = eidx;
    const int* dst = eidx + E;
    float* out = (float*)d_out;
    const int NBC = (N + 1023) / 1024;  // coarse 1024-node buckets

    // Workspace (~25 MB; proven-safe < 51.6 MB)
    char* w = (char*)d_ws;
    size_t Na = ((size_t)N * 4 + 255) & ~(size_t)255;
    size_t Ea = ((size_t)E * 4 + 255) & ~(size_t)255;
    float* disv    = (float*)w;            w += Na;
    int*   row_ptr = (int*)w;              w += Na;
    int*   cnt     = (int*)w;              w += Na;
    int*   countsS = (int*)w;              w += (size_t)MAXNBC * PB * 4;  // 256 KB
    int*   countsD = (int*)w;              w += (size_t)MAXNBC * PB * 4;  // 256 KB
    int*   totalS  = (int*)w;              w += MAXNBC * 4;
    int*   totalD  = (int*)w;              w += MAXNBC * 4;
    int*   baseS   = (int*)w;              w += 256 * 4;
    int*   baseD   = (int*)w;              w += 256 * 4;
    unsigned int* payD   = (unsigned int*)w;   w += Ea;            // 4 MB
    unsigned int* sorted = (unsigned int*)w;   w += Ea;            // 4 MB
    unsigned short* payS = (unsigned short*)w; w += Ea / 2 + 256;  // 2 MB
    unsigned short* Hb   = (unsigned short*)w; w += (size_t)N * 64 * 2;  // 12.8 MB

    const int gG   = (N + 63) / 64;   // gemm tiles
    const int gN16 = (N + 15) / 16;   // aggregate: 16 nodes/block

    // Atomic-free CSR build (graph shared by both layers)
    part_count_kernel<<<PB, THREADS, 0, stream>>>(src, dst, countsS, countsD, E, NBC);
    part_scanblocks_kernel<<<NBC, THREADS, 0, stream>>>(countsS, countsD, totalS, totalD);
    part_scanbase_kernel<<<1, THREADS, 0, stream>>>(totalS, totalD, baseS, baseD, NBC);
    part_scatter_kernel<<<PB, THREADS, 0, stream>>>(src, dst, eattr, countsS, countsD, baseS,
                                                    baseD, payS, payD, E, NBC);
    deg_dis_kernel<<<NBC, THREADS, 0, stream>>>(payS, baseS, totalS, disv, N);
    sort_bucket_kernel<<<NBC, THREADS, 0, stream>>>(payD, baseD, totalD, sorted, row_ptr, cnt, N);

    // layer 1: h -> Hb (bf16), aggregate -> d_out (fp32 temp)
    gemm64_kernel<false><<<gG, THREADS, 0, stream>>>(x, W1, b1, Hb, N);
    aggregate_kernel<<<gN16, THREADS, 0, stream>>>(Hb, disv, ebond1, edir1, row_ptr, cnt,
                                                   sorted, out, N);

    // layer 2 (ReLU fused into GEMM input read): out -> Hb -> out
    gemm64_kernel<true><<<gG, THREADS, 0, stream>>>(out, W2, b2, Hb, N);
    aggregate_kernel<<<gN16, THREADS, 0, stream>>>(Hb, disv, ebond2, edir2, row_ptr, cnt,
                                                   sorted, out, N);
}

// Round 9
// 297.215 us; speedup vs baseline: 3.6510x; 1.0294x over previous
//
#include <hip/hip_runtime.h>

// GCN 2-layer forward (Hu et al. mol-GNN variant) — atomic-free CSR build, bf16 links.
//
//   dis[n] = 1/sqrt(1 + outdeg(n))
//   per layer: h = X@W.T + b   (h stored bf16 — gather traffic is the measured bottleneck)
//              out[n] = dis[n]^2*(h[n]+emb_self) + sum_{e: dst=n} dis[s]*dis[n]*(h[s]+emb_e)
//   Layer-1 aggregate applies ReLU and stores bf16; GEMM2 consumes bf16 directly.
//
// Measured facts:
//  - R4/R6: device-scope random global atomics ~26 G ops/s memory-side RMW -> none used.
//  - R7: aggregate is BW-bound (~3.5 TB/s on the L2-miss path); bytes scale with H row
//    size -> bf16 rows (R8: 339->306 us, absmax 0.0078 vs 0.0519 threshold).
//  - R8: ws_size is 256 MiB (harness d_ws poison fill = 262144 KB dispatches); the R2
//    failure was misattributed to ws overflow. All our kernels are now < 43 us.
// Payload: src(17b) | emb(5b)<<17 | dstLow10(10b)<<22  (unsigned, exactly 32 bits).

#define THREADS 256
#define PB 512     // partition chunk-blocks
#define MAXNBC 128 // max 1024-node coarse buckets (N <= 131072)

__device__ __forceinline__ float bf2f(unsigned short v) {
    return __uint_as_float(((unsigned int)v) << 16);
}
__device__ __forceinline__ unsigned short f2bf(float f) {  // round-to-nearest-even
    unsigned int u = __float_as_uint(f);
    return (unsigned short)((u + 0x7FFFu + ((u >> 16) & 1u)) >> 16);
}

// ---- P1: per-(bucket,block) histograms over src- and dst- coarse buckets ----
__global__ __launch_bounds__(THREADS) void part_count_kernel(
    const int* __restrict__ src, const int* __restrict__ dst,
    int* __restrict__ countsS, int* __restrict__ countsD,  // [NBC*PB] bucket-major
    int E, int NBC) {
    __shared__ int hS[MAXNBC], hD[MAXNBC];
    int t = threadIdx.x, b = blockIdx.x;
    for (int k = t; k < NBC; k += THREADS) { hS[k] = 0; hD[k] = 0; }
    __syncthreads();
    int chunk = (E + PB - 1) / PB;
    int lo = b * chunk, hi = min(E, lo + chunk);
    for (int i = lo + t; i < hi; i += THREADS) {
        atomicAdd(&hS[src[i] >> 10], 1);  // LDS atomic
        atomicAdd(&hD[dst[i] >> 10], 1);  // LDS atomic
    }
    __syncthreads();
    for (int k = t; k < NBC; k += THREADS) {
        countsS[k * PB + b] = hS[k];
        countsD[k * PB + b] = hD[k];
    }
}

// ---- P2a: per-bucket exclusive scan over the PB per-block counts (in place) ----
__global__ __launch_bounds__(THREADS) void part_scanblocks_kernel(
    int* __restrict__ countsS, int* __restrict__ countsD,
    int* __restrict__ totalS, int* __restrict__ totalD) {
    __shared__ int s[THREADS];
    int t = threadIdx.x, k = blockIdx.x;
#pragma unroll 1
    for (int pass = 0; pass < 2; ++pass) {
        int* cp = pass ? countsD : countsS;
        int* tp = pass ? totalD : totalS;
        int base = k * PB + t * 2;
        int v0 = cp[base], v1 = cp[base + 1];
        s[t] = v0 + v1;
        __syncthreads();
        for (int d = 1; d < THREADS; d <<= 1) {
            int a = (t >= d) ? s[t - d] : 0;
            __syncthreads();
            s[t] += a;
            __syncthreads();
        }
        int off = (t == 0) ? 0 : s[t - 1];
        cp[base] = off;
        cp[base + 1] = off + v0;
        if (t == THREADS - 1) tp[k] = s[t];
        __syncthreads();
    }
}

// ---- P2b: exclusive scan of bucket totals -> bucket base offsets (NBC <= 128) ----
__global__ __launch_bounds__(THREADS) void part_scanbase_kernel(
    const int* __restrict__ totalS, const int* __restrict__ totalD,
    int* __restrict__ baseS, int* __restrict__ baseD, int NBC) {
    __shared__ int s[THREADS];
    int t = threadIdx.x;
#pragma unroll 1
    for (int pass = 0; pass < 2; ++pass) {
        const int* in = pass ? totalD : totalS;
        int* out = pass ? baseD : baseS;
        int v = (t < NBC) ? in[t] : 0;
        s[t] = v;
        __syncthreads();
        for (int d = 1; d < THREADS; d <<= 1) {
            int a = (t >= d) ? s[t - d] : 0;
            __syncthreads();
            s[t] += a;
            __syncthreads();
        }
        if (t < NBC) out[t] = s[t] - v;
        __syncthreads();
    }
}

// ---- P3: placement (same chunking as P1), LDS cursors, plain stores ----
__global__ __launch_bounds__(THREADS) void part_scatter_kernel(
    const int* __restrict__ src, const int* __restrict__ dst, const int* __restrict__ attr,
    const int* __restrict__ countsS, const int* __restrict__ countsD,
    const int* __restrict__ baseS, const int* __restrict__ baseD,
    unsigned short* __restrict__ payS, unsigned int* __restrict__ payD, int E, int NBC) {
    __shared__ int curS[MAXNBC], curD[MAXNBC];
    int t = threadIdx.x, b = blockIdx.x;
    for (int k = t; k < NBC; k += THREADS) {
        curS[k] = baseS[k] + countsS[k * PB + b];
        curD[k] = baseD[k] + countsD[k * PB + b];
    }
    __syncthreads();
    int chunk = (E + PB - 1) / PB;
    int lo = b * chunk, hi = min(E, lo + chunk);
    const int2* ap = (const int2*)attr;
    for (int i = lo + t; i < hi; i += THREADS) {
        int sv = src[i], dv = dst[i];
        int2 a = ap[i];
        int pS = atomicAdd(&curS[sv >> 10], 1);  // LDS atomic
        payS[pS] = (unsigned short)(sv & 1023);
        int pD = atomicAdd(&curD[dv >> 10], 1);  // LDS atomic
        payD[pD] = (unsigned int)sv | ((unsigned int)(a.x * 3 + a.y) << 17) |
                   ((unsigned int)(dv & 1023) << 22);
    }
}

// ---- P4+P5 merged: per coarse bucket, (a) out-degree -> dis, (b) counting sort of
// dst edges by node -> sorted entries + per-node row_ptr/cnt. LDS reused across phases.
__global__ __launch_bounds__(THREADS) void build_bucket_kernel(
    const unsigned short* __restrict__ payS, const int* __restrict__ baseS,
    const int* __restrict__ totalS, float* __restrict__ disv,
    const unsigned int* __restrict__ payD, const int* __restrict__ baseD,
    const int* __restrict__ totalD, unsigned int* __restrict__ sorted,
    int* __restrict__ row_ptr, int* __restrict__ cnt_out, int N) {
    __shared__ int cnt[1024], cur[1024];
    __shared__ int s[THREADS];
    int t = threadIdx.x, k = blockIdx.x;

    // phase A: out-degree histogram -> dis
    for (int i = t; i < 1024; i += THREADS) cnt[i] = 0;
    __syncthreads();
    {
        int off = baseS[k], n = totalS[k];
        for (int i = t; i < n; i += THREADS) atomicAdd(&cnt[payS[off + i]], 1);  // LDS atomic
    }
    __syncthreads();
    for (int i = t; i < 1024; i += THREADS) {
        int node = k * 1024 + i;
        if (node < N) disv[node] = 1.0f / sqrtf(1.0f + (float)cnt[i]);
    }
    __syncthreads();

    // phase B: dst counting sort
    for (int i = t; i < 1024; i += THREADS) cnt[i] = 0;
    __syncthreads();
    int eoff = baseD[k], ecnt = totalD[k];
    for (int i = t; i < ecnt; i += THREADS)
        atomicAdd(&cnt[payD[eoff + i] >> 22], 1);  // LDS atomic
    __syncthreads();
    int base4 = t * 4;
    int v0 = cnt[base4], v1 = cnt[base4 + 1], v2 = cnt[base4 + 2], v3 = cnt[base4 + 3];
    s[t] = v0 + v1 + v2 + v3;
    __syncthreads();
    for (int d = 1; d < THREADS; d <<= 1) {
        int a = (t >= d) ? s[t - d] : 0;
        __syncthreads();
        s[t] += a;
        __syncthreads();
    }
    int off = (t == 0) ? 0 : s[t - 1];
    int o0 = off, o1 = off + v0, o2 = o1 + v1, o3 = o2 + v2;
    __syncthreads();
    cur[base4] = o0;
    cur[base4 + 1] = o1;
    cur[base4 + 2] = o2;
    cur[base4 + 3] = o3;
#pragma unroll
    for (int j = 0; j < 4; ++j) {
        int node = k * 1024 + base4 + j;
        if (node < N) {
            row_ptr[node] = eoff + ((j == 0) ? o0 : (j == 1) ? o1 : (j == 2) ? o2 : o3);
            cnt_out[node] = (j == 0) ? v0 : (j == 1) ? v1 : (j == 2) ? v2 : v3;
        }
    }
    __syncthreads();
    for (int i = t; i < ecnt; i += THREADS) {
        unsigned int u = payD[eoff + i];
        int p = atomicAdd(&cur[u >> 22], 1);  // LDS atomic
        sorted[eoff + p] = u & 0x3FFFFFu;     // keep src | emb<<17
    }
}

// ---- GEMM: Hb = bf16(X @ W.T + B). Templated input: fp32 (layer 1) or bf16 (layer 2,
// already ReLU'd by aggregate-1). 4-wave blocks, 64-row tile; wave w owns cols
// [16w,16w+16); W/B reads wave-uniform -> scalar loads; stores staged via LDS.
template <bool XBF16>
__global__ __launch_bounds__(THREADS) void gemm64_kernel(const void* __restrict__ Xv,
                                                         const float* __restrict__ W,
                                                         const float* __restrict__ B,
                                                         unsigned short* __restrict__ Hb,
                                                         int N) {
    __shared__ float smem[64][68];
    int t = threadIdx.x;
    int lane = t & 63;
    int wave = __builtin_amdgcn_readfirstlane(t >> 6);
    int row = blockIdx.x * 64 + lane;

    const float* Wp = W + wave * (16 * 64);
    const float* Bp = B + wave * 16;

    float xr[64];
    if (row < N) {
        if (XBF16) {
            const uint4* xp = (const uint4*)((const unsigned short*)Xv + (size_t)row * 64);
#pragma unroll
            for (int m = 0; m < 8; ++m) {
                uint4 v = xp[m];
                unsigned int a0 = v.x, a1 = v.y, a2 = v.z, a3 = v.w;
                xr[8 * m + 0] = __uint_as_float(a0 << 16);
                xr[8 * m + 1] = __uint_as_float(a0 & 0xFFFF0000u);
                xr[8 * m + 2] = __uint_as_float(a1 << 16);
                xr[8 * m + 3] = __uint_as_float(a1 & 0xFFFF0000u);
                xr[8 * m + 4] = __uint_as_float(a2 << 16);
                xr[8 * m + 5] = __uint_as_float(a2 & 0xFFFF0000u);
                xr[8 * m + 6] = __uint_as_float(a3 << 16);
                xr[8 * m + 7] = __uint_as_float(a3 & 0xFFFF0000u);
            }
        } else {
            const float4* xp = (const float4*)((const float*)Xv + (size_t)row * 64);
#pragma unroll
            for (int m = 0; m < 16; ++m) {
                float4 v = xp[m];
                xr[4 * m + 0] = v.x;
                xr[4 * m + 1] = v.y;
                xr[4 * m + 2] = v.z;
                xr[4 * m + 3] = v.w;
            }
        }
    } else {
#pragma unroll
        for (int k = 0; k < 64; ++k) xr[k] = 0.0f;
    }

    float acc[16];
#pragma unroll
    for (int j = 0; j < 16; ++j) acc[j] = Bp[j];
#pragma unroll
    for (int k = 0; k < 64; ++k) {
        float xk = xr[k];
#pragma unroll
        for (int j = 0; j < 16; ++j) acc[j] = fmaf(xk, Wp[j * 64 + k], acc[j]);
    }

#pragma unroll
    for (int j4 = 0; j4 < 4; ++j4) {
        *(float4*)(&smem[lane][wave * 16 + j4 * 4]) =
            make_float4(acc[4 * j4], acc[4 * j4 + 1], acc[4 * j4 + 2], acc[4 * j4 + 3]);
    }
    __syncthreads();

    // writeout: 512 groups of 8 floats -> 8 bf16; 2 groups/thread
#pragma unroll
    for (int i = 0; i < 2; ++i) {
        int idx = t + i * THREADS;
        int r = idx >> 3;
        int c8 = (idx & 7) << 3;
        int grow = blockIdx.x * 64 + r;
        if (grow < N) {
            ushort4 lo, hi2;
            lo.x = f2bf(smem[r][c8 + 0]);
            lo.y = f2bf(smem[r][c8 + 1]);
            lo.z = f2bf(smem[r][c8 + 2]);
            lo.w = f2bf(smem[r][c8 + 3]);
            hi2.x = f2bf(smem[r][c8 + 4]);
            hi2.y = f2bf(smem[r][c8 + 5]);
            hi2.z = f2bf(smem[r][c8 + 6]);
            hi2.w = f2bf(smem[r][c8 + 7]);
            ushort4* dstp = (ushort4*)(Hb + (size_t)grow * 64 + c8);
            dstp[0] = lo;
            dstp[1] = hi2;
        }
    }
}

// out[n] = dis[n]^2*(Hb[n]+embc[12]) + sum_k dis[s]*dis[n]*(Hb[s]+embc[ei])
// 16 threads/node, 4 dims each; edge loop 2-wide for gather MLP.
// RELU_BF16_OUT: layer-1 epilogue = ReLU + bf16 store; else fp32 store (d_out).
template <bool RELU_BF16_OUT>
__global__ __launch_bounds__(THREADS) void aggregate_kernel(
    const unsigned short* __restrict__ Hb, const float* __restrict__ disv,
    const float* __restrict__ ebond, const float* __restrict__ edir,
    const int* __restrict__ row_ptr, const int* __restrict__ cnt,
    const unsigned int* __restrict__ entries, void* __restrict__ outv, int N) {
    __shared__ float embc[18][64];
    int t = threadIdx.x;
    for (int i = t; i < 18 * 64; i += THREADS) {
        int row = i >> 6, c = i & 63;
        embc[row][c] = ebond[(row / 3) * 64 + c] + edir[(row % 3) * 64 + c];
    }
    __syncthreads();

    int n = blockIdx.x * 16 + (t >> 4);
    if (n >= N) return;
    int c = (t & 15) << 2;

    float dn = disv[n];
    ushort4 hu = *(const ushort4*)(Hb + (size_t)n * 64 + c);
    float4 em = *(const float4*)(&embc[12][c]);  // self-loop: bt=4, bd=0 -> idx 12
    float nrm = dn * dn;
    float4 acc0, acc1;
    acc0.x = nrm * (bf2f(hu.x) + em.x);
    acc0.y = nrm * (bf2f(hu.y) + em.y);
    acc0.z = nrm * (bf2f(hu.z) + em.z);
    acc0.w = nrm * (bf2f(hu.w) + em.w);
    acc1 = make_float4(0.0f, 0.0f, 0.0f, 0.0f);

    int p = row_ptr[n];
    int end = p + cnt[n];
    for (; p + 1 < end; p += 2) {
        unsigned int u0 = entries[p];
        unsigned int u1 = entries[p + 1];
        int s0 = u0 & 0x1FFFF, e0 = (u0 >> 17) & 31;
        int s1 = u1 & 0x1FFFF, e1 = (u1 >> 17) & 31;
        float w0 = disv[s0] * dn;
        float w1 = disv[s1] * dn;
        ushort4 h0 = *(const ushort4*)(Hb + (size_t)s0 * 64 + c);
        ushort4 h1 = *(const ushort4*)(Hb + (size_t)s1 * 64 + c);
        float4 b0 = *(const float4*)(&embc[e0][c]);
        float4 b1 = *(const float4*)(&embc[e1][c]);
        acc0.x = fmaf(w0, bf2f(h0.x) + b0.x, acc0.x);
        acc0.y = fmaf(w0, bf2f(h0.y) + b0.y, acc0.y);
        acc0.z = fmaf(w0, bf2f(h0.z) + b0.z, acc0.z);
        acc0.w = fmaf(w0, bf2f(h0.w) + b0.w, acc0.w);
        acc1.x = fmaf(w1, bf2f(h1.x) + b1.x, acc1.x);
        acc1.y = fmaf(w1, bf2f(h1.y) + b1.y, acc1.y);
        acc1.z = fmaf(w1, bf2f(h1.z) + b1.z, acc1.z);
        acc1.w = fmaf(w1, bf2f(h1.w) + b1.w, acc1.w);
    }
    if (p < end) {
        unsigned int u0 = entries[p];
        int s0 = u0 & 0x1FFFF, e0 = (u0 >> 17) & 31;
        float w0 = disv[s0] * dn;
        ushort4 h0 = *(const ushort4*)(Hb + (size_t)s0 * 64 + c);
        float4 b0 = *(const float4*)(&embc[e0][c]);
        acc0.x = fmaf(w0, bf2f(h0.x) + b0.x, acc0.x);
        acc0.y = fmaf(w0, bf2f(h0.y) + b0.y, acc0.y);
        acc0.z = fmaf(w0, bf2f(h0.z) + b0.z, acc0.z);
        acc0.w = fmaf(w0, bf2f(h0.w) + b0.w, acc0.w);
    }
    acc0.x += acc1.x;
    acc0.y += acc1.y;
    acc0.z += acc1.z;
    acc0.w += acc1.w;

    if (RELU_BF16_OUT) {
        unsigned short* ob = (unsigned short*)outv;
        ushort4 o;
        o.x = f2bf(fmaxf(acc0.x, 0.0f));
        o.y = f2bf(fmaxf(acc0.y, 0.0f));
        o.z = f2bf(fmaxf(acc0.z, 0.0f));
        o.w = f2bf(fmaxf(acc0.w, 0.0f));
        *(ushort4*)(ob + (size_t)n * 64 + c) = o;
    } else {
        float* of = (float*)outv;
        *(float4*)(of + (size_t)n * 64 + c) = acc0;
    }
}

extern "C" void kernel_launch(void* const* d_in, const int* in_sizes, int n_in,
                              void* d_out, int out_size, void* d_ws, size_t ws_size,
                              hipStream_t stream) {
    const float* x      = (const float*)d_in[0];
    const int*   eidx   = (const int*)d_in[1];
    const int*   eattr  = (const int*)d_in[2];
    const float* W1     = (const float*)d_in[3];
    const float* b1     = (const float*)d_in[4];
    const float* ebond1 = (const float*)d_in[5];
    const float* edir1  = (const float*)d_in[6];
    const float* W2     = (const float*)d_in[7];
    const float* b2     = (const float*)d_in[8];
    const float* ebond2 = (const float*)d_in[9];
    const float* edir2  = (const float*)d_in[10];

    const int N = in_sizes[0] / 64;
    const int E = in_sizes[1] / 2;
    const int* src = eidx;
    const int* dst = eidx + E;
    float* out = (float*)d_out;
    const int NBC = (N + 1023) / 1024;  // coarse 1024-node buckets

    // Workspace (~38 MB of 256 MiB)
    char* w = (char*)d_ws;
    size_t Na = ((size_t)N * 4 + 255) & ~(size_t)255;
    size_t Ea = ((size_t)E * 4 + 255) & ~(size_t)255;
    float* disv    = (float*)w;            w += Na;
    int*   row_ptr = (int*)w;              w += Na;
    int*   cnt     = (int*)w;              w += Na;
    int*   countsS = (int*)w;              w += (size_t)MAXNBC * PB * 4;  // 256 KB
    int*   countsD = (int*)w;              w += (size_t)MAXNBC * PB * 4;  // 256 KB
    int*   totalS  = (int*)w;              w += MAXNBC * 4;
    int*   totalD  = (int*)w;              w += MAXNBC * 4;
    int*   baseS   = (int*)w;              w += 256 * 4;
    int*   baseD   = (int*)w;              w += 256 * 4;
    unsigned int* payD   = (unsigned int*)w;   w += Ea;            // 4 MB
    unsigned int* sorted = (unsigned int*)w;   w += Ea;            // 4 MB
    unsigned short* payS = (unsigned short*)w; w += Ea / 2 + 256;  // 2 MB
    unsigned short* Hb   = (unsigned short*)w; w += (size_t)N * 64 * 2;  // 12.8 MB (h)
    unsigned short* Ab   = (unsigned short*)w; w += (size_t)N * 64 * 2;  // 12.8 MB (relu(agg1))

    const int gG   = (N + 63) / 64;   // gemm tiles
    const int gN16 = (N + 15) / 16;   // aggregate: 16 nodes/block

    // Atomic-free CSR build (graph shared by both layers)
    part_count_kernel<<<PB, THREADS, 0, stream>>>(src, dst, countsS, countsD, E, NBC);
    part_scanblocks_kernel<<<NBC, THREADS, 0, stream>>>(countsS, countsD, totalS, totalD);
    part_scanbase_kernel<<<1, THREADS, 0, stream>>>(totalS, totalD, baseS, baseD, NBC);
    part_scatter_kernel<<<PB, THREADS, 0, stream>>>(src, dst, eattr, countsS, countsD, baseS,
                                                    baseD, payS, payD, E, NBC);
    build_bucket_kernel<<<NBC, THREADS, 0, stream>>>(payS, baseS, totalS, disv, payD, baseD,
                                                     totalD, sorted, row_ptr, cnt, N);

    // layer 1: x (fp32) -> Hb (bf16) -> Ab = bf16(relu(aggregate))
    gemm64_kernel<false><<<gG, THREADS, 0, stream>>>(x, W1, b1, Hb, N);
    aggregate_kernel<true><<<gN16, THREADS, 0, stream>>>(Hb, disv, ebond1, edir1, row_ptr, cnt,
                                                         sorted, Ab, N);

    // layer 2: Ab (bf16) -> Hb (bf16) -> d_out (fp32)
    gemm64_kernel<true><<<gG, THREADS, 0, stream>>>(Ab, W2, b2, Hb, N);
    aggregate_kernel<false><<<gN16, THREADS, 0, stream>>>(Hb, disv, ebond2, edir2, row_ptr, cnt,
                                                          sorted, out, N);
}